// Round 9
// baseline (145.091 us; speedup 1.0000x reference)
//
#include <hip/hip_runtime.h>
#include <hip/hip_bf16.h>

#define N 8192
#define F 128
#define L2E 1.44269504f

typedef __attribute__((ext_vector_type(4))) float f32x4;
typedef __attribute__((ext_vector_type(4))) unsigned int u32x4;

// ---------------------------------------------------------------------------
// K1: Wh = h @ W (fp32) + fused c[i] = Wh[i].a2 + p.a3, d[i] = Wh[i].a1 - p.a3.
// 512 blocks x 256 threads, 16 rows/block, W staged in 64 KiB LDS.
// ---------------------------------------------------------------------------
__global__ __launch_bounds__(256) void k_wh(
    const float* __restrict__ h, const float* __restrict__ pos,
    const float* __restrict__ W, const float* __restrict__ a,
    float* __restrict__ Wh, float* __restrict__ cArr, float* __restrict__ dArr)
{
  __shared__ float Ws[128 * 128];
  const int tid = threadIdx.x;
  const int r0  = blockIdx.x * 16;

  {
    f32x4* Ws4 = (f32x4*)Ws;
    const f32x4* Wg4 = (const f32x4*)W;
#pragma unroll
    for (int q = 0; q < 16; ++q) Ws4[q * 256 + tid] = Wg4[q * 256 + tid];
  }
  __syncthreads();

  const int rg  = tid >> 5;    // rows rg*2, rg*2+1
  const int c32 = tid & 31;    // cols c32*4 .. +3

  f32x4 acc0, acc1;
#pragma unroll
  for (int i = 0; i < 4; ++i) { acc0[i] = 0.0f; acc1[i] = 0.0f; }

  const f32x4* h40 = (const f32x4*)(h + (size_t)(r0 + rg * 2) * 128);
  const f32x4* h41 = (const f32x4*)(h + (size_t)(r0 + rg * 2 + 1) * 128);
  const f32x4* Ws4 = (const f32x4*)Ws;

#pragma unroll 4
  for (int k4 = 0; k4 < 32; ++k4) {
    f32x4 hv0 = h40[k4];
    f32x4 hv1 = h41[k4];
#pragma unroll
    for (int e = 0; e < 4; ++e) {
      f32x4 w = Ws4[(k4 * 4 + e) * 32 + c32];
      acc0 += hv0[e] * w;
      acc1 += hv1[e] * w;
    }
  }

  // store Wh rows (coalesced within wave)
  {
    float* wp = Wh + (size_t)(r0 + rg * 2) * 128 + c32 * 4;
    *(f32x4*)wp         = acc0;
    *(f32x4*)(wp + 128) = acc1;
  }

  // fused row dots: s1 = Wh.a1 (j-side d), s2 = Wh.a2 (i-side c)
  f32x4 a1v = *(const f32x4*)(a + c32 * 4);
  f32x4 a2v = *(const f32x4*)(a + 128 + c32 * 4);
#pragma unroll
  for (int rr = 0; rr < 2; ++rr) {
    f32x4 accR = rr ? acc1 : acc0;
    f32x4 t1 = accR * a1v;
    f32x4 t2 = accR * a2v;
    float s1 = t1[0] + t1[1] + t1[2] + t1[3];
    float s2 = t2[0] + t2[1] + t2[2] + t2[3];
#pragma unroll
    for (int m = 1; m < 32; m <<= 1) {
      s1 += __shfl_xor(s1, m);
      s2 += __shfl_xor(s2, m);
    }
    if (c32 == 0) {
      const int row = r0 + rg * 2 + rr;
      float pa = pos[row * 3 + 0] * a[256] + pos[row * 3 + 1] * a[257] +
                 pos[row * 3 + 2] * a[258];
      cArr[row] = s2 + pa;
      dArr[row] = s1 - pa;
    }
  }
}

// ---------------------------------------------------------------------------
// K2: rank-by-counting "sort" of dArr. Each row j gets rank = #{(key,idx) < (mine)};
// scatter sortedD[rank]=d, perm[rank]=j. 256 blocks x 512 thr, 16 lanes/row,
// keys staged in 32 KiB LDS, u32x4 reads (2-way bank alias = free).
// ---------------------------------------------------------------------------
__global__ __launch_bounds__(512) void k_rank(
    const float* __restrict__ dArr, float* __restrict__ sortedD,
    int* __restrict__ perm)
{
  __shared__ unsigned int keyS[N];   // 32 KiB
  const int tid = threadIdx.x;

  // stage keys (monotone sortable transform of float bits)
#pragma unroll
  for (int q = 0; q < 4; ++q) {
    int i4 = q * 512 + tid;
    f32x4 v = ((const f32x4*)dArr)[i4];
    u32x4 kk;
#pragma unroll
    for (int e = 0; e < 4; ++e) {
      union { float f; unsigned u; } cv; cv.f = v[e];
      kk[e] = (cv.u >> 31) ? ~cv.u : (cv.u | 0x80000000u);
    }
    ((u32x4*)keyS)[i4] = kk;
  }
  __syncthreads();

  const int g = tid >> 4;                 // row within block (0..31)
  const int L = tid & 15;
  const int j = blockIdx.x * 32 + g;
  const unsigned int myk = keyS[j];

  int cnt = 0;
#pragma unroll 4
  for (int it = 0; it < 128; ++it) {
    const int u = it * 16 + L;
    u32x4 kv = ((const u32x4*)keyS)[u];
    const int p = u * 4;
#pragma unroll
    for (int e = 0; e < 4; ++e)
      cnt += (kv[e] < myk) || (kv[e] == myk && (p + e) < j);
  }
#pragma unroll
  for (int m = 1; m < 16; m <<= 1) cnt += __shfl_xor(cnt, m);

  if (L == 0) {
    sortedD[cnt] = dArr[j];
    perm[cnt] = j;
  }
}

// ---------------------------------------------------------------------------
// K3: per-chunk totals (64 chunks x 128 sorted positions):
// tA[f] = sum w1*Wh, tB[f] = sum w2*Wh, plus scalar den totals.
// 64 blocks x 256 thr (two 64-m halves combined via LDS).
// ---------------------------------------------------------------------------
__global__ __launch_bounds__(256) void k_scan(
    const float* __restrict__ Wh, const float* __restrict__ sortedD,
    const int* __restrict__ perm, float* __restrict__ chunkTot)
{
  __shared__ float sA[128], sB[128], sdA[2], sdB[2];
  const int tid  = threadIdx.x;
  const int f    = tid & 127;
  const int half = tid >> 7;
  const int base = blockIdx.x * 128 + half * 64;

  float tA = 0, tB = 0, dA = 0, dB = 0;
#pragma unroll 4
  for (int m = 0; m < 64; ++m) {
    float d = sortedD[base + m];
    int row = perm[base + m];
    float w1 = __builtin_amdgcn_exp2f(0.2f * L2E * d);
    float w2 = __builtin_amdgcn_exp2f(L2E * d);
    float v  = Wh[(size_t)row * 128 + f];
    tA += w1 * v; tB += w2 * v; dA += w1; dB += w2;
  }
  if (half == 1) {
    sA[f] = tA; sB[f] = tB;
    if (f == 0) { sdA[1] = dA; sdB[1] = dB; }
  }
  __syncthreads();
  if (half == 0) {
    float* ct = chunkTot + blockIdx.x * 260;
    ct[f]       = tA + sA[f];
    ct[128 + f] = tB + sB[f];
    if (f == 0) { ct[256] = dA + sdA[1]; ct[257] = dB + sdB[1]; }
  }
}

// ---------------------------------------------------------------------------
// K4: emit Apre[k][f] (k=0..N) and Bsuf[k][f] (k=0..N) + scalar den arrays.
// 64 blocks x 256 thr: half 0 runs the ascending A pass, half 1 the
// descending B pass (independent; both accumulate forward -> no cancellation).
// ---------------------------------------------------------------------------
__global__ __launch_bounds__(256) void k_emit(
    const float* __restrict__ Wh, const float* __restrict__ sortedD,
    const int* __restrict__ perm, const float* __restrict__ chunkTot,
    float* __restrict__ Apre, float* __restrict__ Bsuf,
    float* __restrict__ denPre, float* __restrict__ denSuf)
{
  const int tid  = threadIdx.x;
  const int f    = tid & 127;
  const int half = tid >> 7;
  const int c    = blockIdx.x;
  const int base = c * 128;

  if (half == 0) {
    float off = 0, offd = 0;
    for (int cc = 0; cc < c; ++cc) {
      off  += chunkTot[cc * 260 + f];
      offd += chunkTot[cc * 260 + 256];
    }
    if (c == 0) { Apre[f] = 0.0f; if (f == 0) denPre[0] = 0.0f; }
    float Arun = off, dArun = offd;
#pragma unroll 2
    for (int m = 0; m < 128; ++m) {
      float d = sortedD[base + m];
      int row = perm[base + m];
      float v = Wh[(size_t)row * 128 + f];
      float w1 = __builtin_amdgcn_exp2f(0.2f * L2E * d);
      Arun += w1 * v; dArun += w1;
      Apre[(size_t)(base + m + 1) * 128 + f] = Arun;
      if (f == 0) denPre[base + m + 1] = dArun;
    }
  } else {
    float off = 0, offd = 0;
    for (int cc = c + 1; cc < 64; ++cc) {
      off  += chunkTot[cc * 260 + 128 + f];
      offd += chunkTot[cc * 260 + 257];
    }
    if (c == 63) { Bsuf[(size_t)N * 128 + f] = 0.0f; if (f == 0) denSuf[N] = 0.0f; }
    float Brun = off, dBrun = offd;
#pragma unroll 2
    for (int m = 127; m >= 0; --m) {
      float d = sortedD[base + m];
      int row = perm[base + m];
      float v = Wh[(size_t)row * 128 + f];
      float w2 = __builtin_amdgcn_exp2f(L2E * d);
      Brun += w2 * v; dBrun += w2;
      Bsuf[(size_t)(base + m) * 128 + f] = Brun;
      if (f == 0) denSuf[base + m] = dBrun;
    }
  }
}

// ---------------------------------------------------------------------------
// K5: per row i: k = upper_bound(sortedD, -c_i) via 13-step LDS binary search;
// out = ELU((e2*Apre[k] + e1*Bsuf[k]) / (e2*denPre[k] + e1*denSuf[k])).
// 128 blocks x 256 thr, 32 lanes per row, 64 rows/block.
// ---------------------------------------------------------------------------
__global__ __launch_bounds__(256) void k_out(
    const float* __restrict__ cArr, const float* __restrict__ sortedD,
    const float* __restrict__ Apre, const float* __restrict__ Bsuf,
    const float* __restrict__ denPre, const float* __restrict__ denSuf,
    float* __restrict__ out)
{
  __shared__ float sd[N];   // 32 KiB
  const int tid = threadIdx.x;
#pragma unroll
  for (int q = 0; q < 8; ++q)
    ((f32x4*)sd)[q * 256 + tid] = ((const f32x4*)sortedD)[q * 256 + tid];
  __syncthreads();

  const int grp = tid >> 5;
  const int cl  = tid & 31;
#pragma unroll
  for (int pass = 0; pass < 8; ++pass) {
    const int r = blockIdx.x * 64 + pass * 8 + grp;
    const float c = cArr[r];
    const float t = -c;
    int lo = 0, hi = N;
#pragma unroll
    for (int it = 0; it < 13; ++it) {
      int mid = (lo + hi) >> 1;
      if (sd[mid] <= t) lo = mid + 1; else hi = mid;
    }
    const int k = lo;
    const float e2 = __builtin_amdgcn_exp2f(0.2f * L2E * c);
    const float e1 = __builtin_amdgcn_exp2f(L2E * c);
    f32x4 A4 = *(const f32x4*)(Apre + (size_t)k * 128 + cl * 4);
    f32x4 B4 = *(const f32x4*)(Bsuf + (size_t)k * 128 + cl * 4);
    const float den = e2 * denPre[k] + e1 * denSuf[k];
    const float inv = 1.0f / den;
    f32x4 o;
#pragma unroll
    for (int i = 0; i < 4; ++i) {
      float x = (e2 * A4[i] + e1 * B4[i]) * inv;
      o[i] = x > 0.0f ? x : (__builtin_amdgcn_exp2f(x * L2E) - 1.0f);
    }
    *(f32x4*)(out + (size_t)r * 128 + cl * 4) = o;
  }
}

extern "C" void kernel_launch(void* const* d_in, const int* in_sizes, int n_in,
                              void* d_out, int out_size, void* d_ws, size_t ws_size,
                              hipStream_t stream)
{
  const float* h   = (const float*)d_in[0];
  const float* pos = (const float*)d_in[1];
  const float* W   = (const float*)d_in[2];
  const float* a   = (const float*)d_in[3];
  float* out = (float*)d_out;

  float* ws = (float*)d_ws;
  size_t off = 0;
  float* Wh      = ws + off; off += (size_t)N * F;        // 4 MiB
  float* cArr    = ws + off; off += N;
  float* dArr    = ws + off; off += N;
  float* sortedD = ws + off; off += N;
  int*   perm    = (int*)(ws + off); off += N;
  float* denPre  = ws + off; off += N + 8;
  float* denSuf  = ws + off; off += N + 8;
  float* chunkTot= ws + off; off += 64 * 260;
  float* Apre    = ws + off; off += (size_t)(N + 1) * F + 32;
  float* Bsuf    = ws + off; off += (size_t)(N + 1) * F + 32;

  hipLaunchKernelGGL(k_wh,   dim3(512), dim3(256), 0, stream,
                     h, pos, W, a, Wh, cArr, dArr);
  hipLaunchKernelGGL(k_rank, dim3(256), dim3(512), 0, stream,
                     dArr, sortedD, perm);
  hipLaunchKernelGGL(k_scan, dim3(64), dim3(256), 0, stream,
                     Wh, sortedD, perm, chunkTot);
  hipLaunchKernelGGL(k_emit, dim3(64), dim3(256), 0, stream,
                     Wh, sortedD, perm, chunkTot, Apre, Bsuf, denPre, denSuf);
  hipLaunchKernelGGL(k_out,  dim3(128), dim3(256), 0, stream,
                     cArr, sortedD, Apre, Bsuf, denPre, denSuf, out);
}

// Round 10
// 126.306 us; speedup vs baseline: 1.1487x; 1.1487x over previous
//
#include <hip/hip_runtime.h>
#include <hip/hip_bf16.h>

#define N 8192
#define F 128
#define L2E 1.44269504f
#define NCH 512              // chunks
#define CHL 16               // elems per chunk

typedef __attribute__((ext_vector_type(4))) float f32x4;
typedef __attribute__((ext_vector_type(4))) unsigned int u32x4;
typedef __attribute__((ext_vector_type(4))) int i32x4;

// ---------------------------------------------------------------------------
// K1: Wh = h @ W (fp32) + fused c[i] = Wh[i].a2 + p.a3, d[i] = Wh[i].a1 - p.a3.
// 512 blocks x 256 threads, 16 rows/block, W staged in 64 KiB LDS.
// ---------------------------------------------------------------------------
__global__ __launch_bounds__(256) void k_wh(
    const float* __restrict__ h, const float* __restrict__ pos,
    const float* __restrict__ W, const float* __restrict__ a,
    float* __restrict__ Wh, float* __restrict__ cArr, float* __restrict__ dArr)
{
  __shared__ float Ws[128 * 128];
  const int tid = threadIdx.x;
  const int r0  = blockIdx.x * 16;

  {
    f32x4* Ws4 = (f32x4*)Ws;
    const f32x4* Wg4 = (const f32x4*)W;
#pragma unroll
    for (int q = 0; q < 16; ++q) Ws4[q * 256 + tid] = Wg4[q * 256 + tid];
  }
  __syncthreads();

  const int rg  = tid >> 5;    // rows rg*2, rg*2+1
  const int c32 = tid & 31;    // cols c32*4 .. +3

  f32x4 acc0, acc1;
#pragma unroll
  for (int i = 0; i < 4; ++i) { acc0[i] = 0.0f; acc1[i] = 0.0f; }

  const f32x4* h40 = (const f32x4*)(h + (size_t)(r0 + rg * 2) * 128);
  const f32x4* h41 = (const f32x4*)(h + (size_t)(r0 + rg * 2 + 1) * 128);
  const f32x4* Ws4 = (const f32x4*)Ws;

#pragma unroll 4
  for (int k4 = 0; k4 < 32; ++k4) {
    f32x4 hv0 = h40[k4];
    f32x4 hv1 = h41[k4];
#pragma unroll
    for (int e = 0; e < 4; ++e) {
      f32x4 w = Ws4[(k4 * 4 + e) * 32 + c32];
      acc0 += hv0[e] * w;
      acc1 += hv1[e] * w;
    }
  }

  {
    float* wp = Wh + (size_t)(r0 + rg * 2) * 128 + c32 * 4;
    *(f32x4*)wp         = acc0;
    *(f32x4*)(wp + 128) = acc1;
  }

  f32x4 a1v = *(const f32x4*)(a + c32 * 4);
  f32x4 a2v = *(const f32x4*)(a + 128 + c32 * 4);
#pragma unroll
  for (int rr = 0; rr < 2; ++rr) {
    f32x4 accR = rr ? acc1 : acc0;
    f32x4 t1 = accR * a1v;
    f32x4 t2 = accR * a2v;
    float s1 = t1[0] + t1[1] + t1[2] + t1[3];
    float s2 = t2[0] + t2[1] + t2[2] + t2[3];
#pragma unroll
    for (int m = 1; m < 32; m <<= 1) {
      s1 += __shfl_xor(s1, m);
      s2 += __shfl_xor(s2, m);
    }
    if (c32 == 0) {
      const int row = r0 + rg * 2 + rr;
      float pa = pos[row * 3 + 0] * a[256] + pos[row * 3 + 1] * a[257] +
                 pos[row * 3 + 2] * a[258];
      cArr[row] = s2 + pa;
      dArr[row] = s1 - pa;
    }
  }
}

// ---------------------------------------------------------------------------
// K2: rank-by-counting sort of dArr (tie-broken by index). 256 blocks x 512
// thr, 16 lanes per row, keys staged in 32 KiB LDS.
// ---------------------------------------------------------------------------
__global__ __launch_bounds__(512) void k_rank(
    const float* __restrict__ dArr, float* __restrict__ sortedD,
    int* __restrict__ perm)
{
  __shared__ unsigned int keyS[N];   // 32 KiB
  const int tid = threadIdx.x;

#pragma unroll
  for (int q = 0; q < 4; ++q) {
    int i4 = q * 512 + tid;
    f32x4 v = ((const f32x4*)dArr)[i4];
    u32x4 kk;
#pragma unroll
    for (int e = 0; e < 4; ++e) {
      union { float f; unsigned u; } cv; cv.f = v[e];
      kk[e] = (cv.u >> 31) ? ~cv.u : (cv.u | 0x80000000u);
    }
    ((u32x4*)keyS)[i4] = kk;
  }
  __syncthreads();

  const int g = tid >> 4;                 // row within block (0..31)
  const int L = tid & 15;
  const int j = blockIdx.x * 32 + g;
  const unsigned int myk = keyS[j];

  int cnt = 0;
#pragma unroll 4
  for (int it = 0; it < 128; ++it) {
    const int u = it * 16 + L;
    u32x4 kv = ((const u32x4*)keyS)[u];
    const int p = u * 4;
#pragma unroll
    for (int e = 0; e < 4; ++e)
      cnt += (kv[e] < myk) || (kv[e] == myk && (p + e) < j);
  }
#pragma unroll
  for (int m = 1; m < 16; m <<= 1) cnt += __shfl_xor(cnt, m);

  if (L == 0) {
    sortedD[cnt] = dArr[j];
    perm[cnt] = j;
  }
}

// ---------------------------------------------------------------------------
// K3: per-chunk totals, 512 chunks x 16 sorted positions.
// TA[c][f] = sum w1*Wh (slope branch), TB[c][f] = sum w2*Wh (linear branch),
// denT[c] = scalar den pair. 256 blocks x 256 thr (2 chunks/block).
// ---------------------------------------------------------------------------
__global__ __launch_bounds__(256) void k_ctot(
    const float* __restrict__ Wh, const float* __restrict__ sortedD,
    const int* __restrict__ perm, float* __restrict__ TA,
    float* __restrict__ TB, float* __restrict__ denT)
{
  const int tid = threadIdx.x;
  const int f   = tid & 127;
  const int c   = blockIdx.x * 2 + (tid >> 7);
  const int base = c * CHL;

  float tA = 0, tB = 0, dA = 0, dB = 0;
#pragma unroll
  for (int m = 0; m < CHL; ++m) {
    float d = sortedD[base + m];
    int row = perm[base + m];
    float w1 = __builtin_amdgcn_exp2f(0.2f * L2E * d);
    float w2 = __builtin_amdgcn_exp2f(L2E * d);
    float v  = Wh[(size_t)row * F + f];
    tA += w1 * v; tB += w2 * v; dA += w1; dB += w2;
  }
  TA[c * F + f] = tA;
  TB[c * F + f] = tB;
  if (f == 0) { denT[c * 2] = dA; denT[c * 2 + 1] = dB; }
}

// ---------------------------------------------------------------------------
// K4: scans over the 512 chunk totals. Blocks 0..127: per-f exclusive prefix
// (preA) and inclusive suffix (sufB, with sufB[NCH]=0). Block 128: scalar dens.
// Hillis-Steele in LDS, 512 threads.
// ---------------------------------------------------------------------------
__global__ __launch_bounds__(512) void k_cpre(
    const float* __restrict__ TA, const float* __restrict__ TB,
    const float* __restrict__ denT, float* __restrict__ preA,
    float* __restrict__ sufB, float* __restrict__ denPre,
    float* __restrict__ denSuf)
{
  __shared__ float sA[NCH], sB[NCH];
  const int c = threadIdx.x;
  float a, b;
  if (blockIdx.x < 128) {
    a = TA[c * F + blockIdx.x];
    b = TB[c * F + blockIdx.x];
  } else {
    a = denT[c * 2];
    b = denT[c * 2 + 1];
  }
  sA[c] = a; sB[c] = b;
  __syncthreads();
  float ia = a, ib = b;
  for (int s = 1; s < NCH; s <<= 1) {
    float xa = 0, xb = 0;
    if (c >= s) { xa = sA[c - s]; xb = sB[c - s]; }
    __syncthreads();
    ia += xa; ib += xb;
    sA[c] = ia; sB[c] = ib;
    __syncthreads();
  }
  const float totB = sB[NCH - 1];
  if (blockIdx.x < 128) {
    const int f = blockIdx.x;
    preA[(size_t)c * F + f] = ia - a;                 // exclusive prefix
    sufB[(size_t)c * F + f] = totB - ib + b;          // inclusive suffix
    if (c == NCH - 1) sufB[(size_t)NCH * F + f] = 0.0f;
  } else {
    denPre[c] = ia - a;
    denSuf[c] = totB - ib + b;
    if (c == NCH - 1) denSuf[NCH] = 0.0f;
  }
}

// ---------------------------------------------------------------------------
// K5: per row i: k = #{d <= -c_i} via LDS binary search; reconstruct
// A(k), B(k) = chunk-boundary prefix/suffix + <=16-elem partial chunk scan;
// out = ELU((e2*A + e1*B) / (e2*denA + e1*denB)).
// 256 blocks x 256 thr, 32 rows/block, sd+perm staged in 64 KiB LDS.
// ---------------------------------------------------------------------------
__global__ __launch_bounds__(256) void k_out(
    const float* __restrict__ cArr, const float* __restrict__ sortedD,
    const int* __restrict__ perm, const float* __restrict__ Wh,
    const float* __restrict__ preA, const float* __restrict__ sufB,
    const float* __restrict__ denPre, const float* __restrict__ denSuf,
    float* __restrict__ out)
{
  __shared__ float sd[N];   // 32 KiB
  __shared__ int   pm[N];   // 32 KiB
  const int tid = threadIdx.x;
#pragma unroll
  for (int q = 0; q < 8; ++q) {
    ((f32x4*)sd)[q * 256 + tid] = ((const f32x4*)sortedD)[q * 256 + tid];
    ((i32x4*)pm)[q * 256 + tid] = ((const i32x4*)perm)[q * 256 + tid];
  }
  __syncthreads();

  const int grp = tid >> 5;
  const int cl  = tid & 31;
#pragma unroll
  for (int pass = 0; pass < 4; ++pass) {
    const int r = blockIdx.x * 32 + pass * 8 + grp;
    const float cv = cArr[r];
    const float t = -cv;
    int lo = 0, hi = N;
#pragma unroll
    for (int it = 0; it < 13; ++it) {
      int mid = (lo + hi) >> 1;
      if (sd[mid] <= t) lo = mid + 1; else hi = mid;
    }
    const int k  = lo;
    const int cc = (k >> 4) > (NCH - 1) ? (NCH - 1) : (k >> 4);
    const int rem = k - cc * CHL;                    // 0..16

    f32x4 A4 = *(const f32x4*)(preA + (size_t)cc * F + cl * 4);
    f32x4 B4 = *(const f32x4*)(sufB + (size_t)(cc + 1) * F + cl * 4);
    float dA = denPre[cc], dB = denSuf[cc + 1];

#pragma unroll
    for (int m = 0; m < CHL; ++m) {
      float d  = sd[cc * CHL + m];
      int row  = pm[cc * CHL + m];
      f32x4 v  = *(const f32x4*)(Wh + (size_t)row * F + cl * 4);
      float w1 = __builtin_amdgcn_exp2f(0.2f * L2E * d);
      float w2 = __builtin_amdgcn_exp2f(L2E * d);
      if (m < rem) { A4 += w1 * v; dA += w1; }
      else         { B4 += w2 * v; dB += w2; }
    }

    const float e2 = __builtin_amdgcn_exp2f(0.2f * L2E * cv);
    const float e1 = __builtin_amdgcn_exp2f(L2E * cv);
    const float den = e2 * dA + e1 * dB;
    const float inv = 1.0f / den;
    f32x4 o;
#pragma unroll
    for (int i = 0; i < 4; ++i) {
      float x = (e2 * A4[i] + e1 * B4[i]) * inv;
      o[i] = x > 0.0f ? x : (__builtin_amdgcn_exp2f(x * L2E) - 1.0f);
    }
    *(f32x4*)(out + (size_t)r * F + cl * 4) = o;
  }
}

extern "C" void kernel_launch(void* const* d_in, const int* in_sizes, int n_in,
                              void* d_out, int out_size, void* d_ws, size_t ws_size,
                              hipStream_t stream)
{
  const float* h   = (const float*)d_in[0];
  const float* pos = (const float*)d_in[1];
  const float* W   = (const float*)d_in[2];
  const float* a   = (const float*)d_in[3];
  float* out = (float*)d_out;

  float* ws = (float*)d_ws;
  size_t off = 0;
  float* Wh      = ws + off; off += (size_t)N * F;         // 4 MiB
  float* cArr    = ws + off; off += N;
  float* dArr    = ws + off; off += N;
  float* sortedD = ws + off; off += N;
  int*   perm    = (int*)(ws + off); off += N;
  float* TA      = ws + off; off += (size_t)NCH * F;
  float* TB      = ws + off; off += (size_t)NCH * F;
  float* denT    = ws + off; off += NCH * 2;
  float* preA    = ws + off; off += (size_t)NCH * F;
  float* sufB    = ws + off; off += (size_t)(NCH + 1) * F;
  float* denPre  = ws + off; off += NCH + 8;
  float* denSuf  = ws + off; off += NCH + 8;

  hipLaunchKernelGGL(k_wh,   dim3(512), dim3(256), 0, stream,
                     h, pos, W, a, Wh, cArr, dArr);
  hipLaunchKernelGGL(k_rank, dim3(256), dim3(512), 0, stream,
                     dArr, sortedD, perm);
  hipLaunchKernelGGL(k_ctot, dim3(256), dim3(256), 0, stream,
                     Wh, sortedD, perm, TA, TB, denT);
  hipLaunchKernelGGL(k_cpre, dim3(129), dim3(512), 0, stream,
                     TA, TB, denT, preA, sufB, denPre, denSuf);
  hipLaunchKernelGGL(k_out,  dim3(256), dim3(256), 0, stream,
                     cArr, sortedD, perm, Wh, preA, sufB, denPre, denSuf, out);
}